// Round 9
// baseline (40.358 us; speedup 1.0000x reference)
//
#include <hip/hip_runtime.h>

// RNNFFT: depth-10 radix-2 butterfly network over last dim (1024).
// v = x; for l = 9..0: y = B_l(w_l * v); v = (l==1) ? y : x + y
// Pairs at level l: (e, e^h), h = 512>>l. Twiddle: bw[OFF[l] + (e & (n_l-1))].
// Mix (einsum 'ij,...ik->...jk' => lw^T): role-j: y = lw[j][j]*t_self + lw[1-j][j]*t_partner.
// One wave handles NV=2 vectors, 16 elems/lane each (e = lane*16 + r):
//   levels 9..6: in-register pairs (r, r^h), lane-uniform twiddles (scalar loads)
//   levels 5..0: cross-lane exchange, lane mask 32>>l:
//     mask 1  -> DPP quad_perm [1,0,3,2] (0xB1)      [canonical]
//     mask 2  -> DPP quad_perm [2,3,0,1] (0x4E)      [canonical]
//     mask 4/8/16 -> ds_swizzle 0x101F/0x201F/0x401F [ISA-doc butterfly offsets]
//     mask 32 -> __shfl_xor (REVERTED from permlane32_swap: r7/r8 absmax 0.09375
//                bit-identical across different fma arrangements while r4's
//                shfl_xor version was 0.0 -> suspect the hand-derived permlane
//                select; this round tests that theory)
// Twiddles for cross levels staged in LDS once per block (r8: -5us), XOR-swizzled
// (f ^ ((f>>5)&7)<<2) to break the stride-64B bank pattern.
// R8 post-mortem: latency-bound - one serial 10-level chain/wave, ~3 waves/SIMD
// resident. This round: NV=2 independent chains per wave (2x ILP at every level),
// waves_per_eu(2,4) -> 256-VGPR budget so the ~120-reg live set fits (r3's NV=2
// spilled at the 128 cap from launch_bounds(256,4)).

constexpr int VECLEN = 1024;
constexpr int NV = 2;

__device__ __forceinline__ int swz(int f) {      // LDS anti-conflict swizzle (float idx)
  return f ^ (((f >> 5) & 7) << 2);              // xor bits[4:2] <- bits[7:5]; keeps 16B groups
}

template<int L>
__device__ __forceinline__ float partner(float t, int lane) {
  const int ti = __float_as_int(t);
  if constexpr (L == 5) {          // lane ^ 1
    return __int_as_float(__builtin_amdgcn_update_dpp(0, ti, 0xB1, 0xF, 0xF, true));
  } else if constexpr (L == 4) {   // lane ^ 2
    return __int_as_float(__builtin_amdgcn_update_dpp(0, ti, 0x4E, 0xF, 0xF, true));
  } else if constexpr (L == 3) {   // lane ^ 4
    return __int_as_float(__builtin_amdgcn_ds_swizzle(ti, 0x101F));
  } else if constexpr (L == 2) {   // lane ^ 8
    return __int_as_float(__builtin_amdgcn_ds_swizzle(ti, 0x201F));
  } else if constexpr (L == 1) {   // lane ^ 16
    return __int_as_float(__builtin_amdgcn_ds_swizzle(ti, 0x401F));
  } else {                         // L == 0: lane ^ 32 (known-exact path)
    return __shfl_xor(t, 32, 64);
  }
}

template<int L, bool RESL>
__device__ __forceinline__ void level_inlane(float (&v)[NV][16], const float (&xr)[NV][16],
                                             const float* __restrict__ bw,
                                             const float* __restrict__ lw) {
  constexpr int n = VECLEN >> L;          // 16, 8, 4, 2
  constexpr int h = n >> 1;               // 8, 4, 2, 1
  constexpr int off = 2048 - (2048 >> L); // OFFSETS[L]
  float w[n];                              // lane-uniform -> scalar loads
#pragma unroll
  for (int i = 0; i < n; ++i) w[i] = bw[off + i];
  const float l00 = lw[L * 4 + 0], l01 = lw[L * 4 + 1];
  const float l10 = lw[L * 4 + 2], l11 = lw[L * 4 + 3];
#pragma unroll
  for (int u = 0; u < NV; ++u) {
#pragma unroll
    for (int r = 0; r < 16; ++r) {
      if ((r & h) == 0) {
        const int q = r ^ h;
        const float t0 = w[r & (n - 1)] * v[u][r];
        const float t1 = w[q & (n - 1)] * v[u][q];
        const float y0 = l00 * t0 + l10 * t1;   // role 0  (exact r1/r4 ordering)
        const float y1 = l01 * t0 + l11 * t1;   // role 1
        v[u][r] = RESL ? xr[u][r] + y0 : y0;
        v[u][q] = RESL ? xr[u][q] + y1 : y1;
      }
    }
  }
}

template<int L, bool RESL>
__device__ __forceinline__ void level_cross(float (&v)[NV][16], const float (&xr)[NV][16],
                                            const float (&w)[16],
                                            const float* __restrict__ lw, int lane) {
  const int role = (lane >> (5 - L)) & 1;
  const float l00 = lw[L * 4 + 0], l01 = lw[L * 4 + 1];
  const float l10 = lw[L * 4 + 2], l11 = lw[L * 4 + 3];
  const float cs = role ? l11 : l00;      // coeff on own t
  const float cp = role ? l01 : l10;      // coeff on partner t
#pragma unroll
  for (int u = 0; u < NV; ++u) {
#pragma unroll
    for (int r = 0; r < 16; ++r) {
      const float t = w[r] * v[u][r];
      const float tp = partner<L>(t, lane);
      const float y = cs * t + cp * tp;   // exact r1/r4 ordering
      v[u][r] = RESL ? xr[u][r] + y : y;
    }
  }
}

template<int L>
__device__ __forceinline__ void loadw_lds(float (&w)[16], const float* lds_bw, int lane) {
  constexpr int n = VECLEN >> L;
  constexpr int off = 2048 - (2048 >> L);  // OFFSETS[L]
  const int f0 = off + ((lane * 16) & (n - 1));
#pragma unroll
  for (int k = 0; k < 4; ++k) {
    const int g = swz(f0 + 4 * k);         // 16B-aligned group preserved
    const float4 f = *reinterpret_cast<const float4*>(lds_bw + g);
    w[4 * k + 0] = f.x; w[4 * k + 1] = f.y; w[4 * k + 2] = f.z; w[4 * k + 3] = f.w;
  }
}

__global__ __launch_bounds__(256)
__attribute__((amdgpu_waves_per_eu(2, 4)))
void rnnfft_kernel(const float* __restrict__ x,
                   const float* __restrict__ bw,
                   const float* __restrict__ lw,
                   float* __restrict__ out, int nvec) {
  __shared__ float lds_bw[2016];           // cross levels use floats [0, 2016)
  const int t = threadIdx.x;
  const int wid = blockIdx.x * 4 + (t >> 6);   // wave id; vectors [2*wid, 2*wid+1]
  const int lane = t & 63;
  const size_t base = (size_t)wid * (VECLEN * NV) + lane * 16;

  // Issue all 8 x-loads first so their latency overlaps the staging.
  float v[NV][16], xr[NV][16];
#pragma unroll
  for (int u = 0; u < NV; ++u) {
#pragma unroll
    for (int k = 0; k < 4; ++k) {
      const float4 f = *reinterpret_cast<const float4*>(x + base + u * VECLEN + 4 * k);
      xr[u][4 * k + 0] = f.x; xr[u][4 * k + 1] = f.y;
      xr[u][4 * k + 2] = f.z; xr[u][4 * k + 3] = f.w;
    }
  }

  // Stage bw[0..2016) into LDS (swizzled), once per block.
  if (t < 252) {
    const float4 a = *reinterpret_cast<const float4*>(bw + 8 * t);
    const float4 b = *reinterpret_cast<const float4*>(bw + 8 * t + 4);
    *reinterpret_cast<float4*>(lds_bw + swz(8 * t)) = a;
    *reinterpret_cast<float4*>(lds_bw + swz(8 * t + 4)) = b;
  }
  __syncthreads();

#pragma unroll
  for (int u = 0; u < NV; ++u)
#pragma unroll
    for (int r = 0; r < 16; ++r) v[u][r] = xr[u][r];

  // Prefetch twiddles for the first two cross levels from LDS.
  float wA[16], wB[16];
  loadw_lds<5>(wA, lds_bw, lane);
  loadw_lds<4>(wB, lds_bw, lane);

  // Deepest level first (adjacent pairs), unwinding to level 0 (halves).
  level_inlane<9, true >(v, xr, bw, lw);
  level_inlane<8, true >(v, xr, bw, lw);
  level_inlane<7, true >(v, xr, bw, lw);
  level_inlane<6, true >(v, xr, bw, lw);

  level_cross<5, true >(v, xr, wA, lw, lane);
  loadw_lds<3>(wA, lds_bw, lane);
  level_cross<4, true >(v, xr, wB, lw, lane);
  loadw_lds<2>(wB, lds_bw, lane);
  level_cross<3, true >(v, xr, wA, lw, lane);
  loadw_lds<1>(wA, lds_bw, lane);
  level_cross<2, true >(v, xr, wB, lw, lane);
  loadw_lds<0>(wB, lds_bw, lane);
  level_cross<1, false>(v, xr, wA, lw, lane);  // RES[1] = False
  level_cross<0, true >(v, xr, wB, lw, lane);

#pragma unroll
  for (int u = 0; u < NV; ++u) {
#pragma unroll
    for (int k = 0; k < 4; ++k) {
      float4 f;
      f.x = v[u][4 * k + 0]; f.y = v[u][4 * k + 1];
      f.z = v[u][4 * k + 2]; f.w = v[u][4 * k + 3];
      *reinterpret_cast<float4*>(out + base + u * VECLEN + 4 * k) = f;
    }
  }
}

extern "C" void kernel_launch(void* const* d_in, const int* in_sizes, int n_in,
                              void* d_out, int out_size, void* d_ws, size_t ws_size,
                              hipStream_t stream) {
  const float* x  = (const float*)d_in[0];
  const float* bw = (const float*)d_in[1];
  const float* lw = (const float*)d_in[2];
  float* out = (float*)d_out;
  const int nvec = in_sizes[0] / VECLEN;        // 16384 vectors
  const int nwave = nvec / NV;                  // 8192 waves
  const int wpb = 4;                            // waves per block (256 threads)
  const int blocks = (nwave + wpb - 1) / wpb;   // 2048, exact
  rnnfft_kernel<<<blocks, 256, 0, stream>>>(x, bw, lw, out, nvec);
}

// Round 11
// 31.049 us; speedup vs baseline: 1.2998x; 1.2998x over previous
//
#include <hip/hip_runtime.h>

// RNNFFT: depth-10 radix-2 butterfly network over last dim (1024).
// v = x; for l = 9..0: y = B_l(w_l * v); v = (l==1) ? y : x + y
// Pairs at level l: (e, e^h), h = 512>>l. Twiddle: bw[OFF[l] + (e & (n_l-1))].
// Mix (lw^T): role-j: y = lw[j][j]*t_self + lw[1-j][j]*t_partner; role = (e>>log2 h)&1.
//
// R9 post-mortem: time pinned ~40-50us across r1-r9 while VALU work ~10us and HBM
// ~16-20us -> serialized on 6 dependent cross-lane DS round trips per wave.
// This round: TWO-LAYOUT butterfly, zero serial DS exchanges:
//   Layout A (e = lane*16 + r): levels 9..6 in-lane; levels 5,4 = lane-mask 1,2
//     -> DPP quad_perm (zero-latency VALU).
//   ONE LDS transpose A->B per wave (XOR-swizzled, conflict-free-ish).
//   Layout B (e = r*64 + lane): levels 3..0 (h=512..64) flip r-bits -> in-lane VALU.
// Residual x loaded in BOTH layouts at kernel start (same cachelines, L2 hits);
// output stored directly in B-layout (16 x 256B coalesced dword stores).
// All arithmetic per element identical to r4 (absmax 0.0 ordering).
// Numerics history: permlane32_swap select was the 0.09375 bug (r9 confirmed);
// DPP 0xB1/0x4E are exact.

constexpr int VECLEN = 1024;

__device__ __forceinline__ int swz(int f) {      // XOR bits[4:2] with bits[7:5]
  return f ^ (((f >> 5) & 7) << 2);              // preserves 16B groups
}

// A-layout in-lane levels (9..6), lane-uniform twiddles (scalar loads from global).
template<int L, bool RESL>
__device__ __forceinline__ void level_inlane(float (&v)[16], const float (&xr)[16],
                                             const float* __restrict__ bw,
                                             const float* __restrict__ lw) {
  constexpr int n = VECLEN >> L;          // 16, 8, 4, 2
  constexpr int h = n >> 1;               // 8, 4, 2, 1
  constexpr int off = 2048 - (2048 >> L); // OFFSETS[L]
  float w[n];
#pragma unroll
  for (int i = 0; i < n; ++i) w[i] = bw[off + i];
  const float l00 = lw[L*4+0], l01 = lw[L*4+1], l10 = lw[L*4+2], l11 = lw[L*4+3];
#pragma unroll
  for (int r = 0; r < 16; ++r) {
    if ((r & h) == 0) {
      const int q = r ^ h;
      const float t0 = w[r & (n-1)] * v[r];
      const float t1 = w[q & (n-1)] * v[q];
      const float y0 = l00*t0 + l10*t1;   // role 0 (exact r4 ordering)
      const float y1 = l01*t0 + l11*t1;   // role 1
      v[r] = RESL ? xr[r] + y0 : y0;
      v[q] = RESL ? xr[q] + y1 : y1;
    }
  }
}

// A-layout DPP cross levels: L=5 -> lane^1 (quad_perm 0xB1), L=4 -> lane^2 (0x4E).
template<int L, bool RESL>
__device__ __forceinline__ void level_dpp(float (&v)[16], const float (&xr)[16],
                                          const float (&w)[16],
                                          const float* __restrict__ lw, int lane) {
  static_assert(L == 4 || L == 5, "DPP levels only");
  const int role = (lane >> (5 - L)) & 1;
  const float l00 = lw[L*4+0], l01 = lw[L*4+1], l10 = lw[L*4+2], l11 = lw[L*4+3];
  const float cs = role ? l11 : l00;      // coeff on own t
  const float cp = role ? l01 : l10;      // coeff on partner t
#pragma unroll
  for (int r = 0; r < 16; ++r) {
    const float t = w[r] * v[r];
    const int ti = __float_as_int(t);
    const int pi = (L == 5)
      ? __builtin_amdgcn_update_dpp(0, ti, 0xB1, 0xF, 0xF, true)   // [1,0,3,2]
      : __builtin_amdgcn_update_dpp(0, ti, 0x4E, 0xF, 0xF, true);  // [2,3,0,1]
    const float tp = __int_as_float(pi);
    const float y = cs*t + cp*tp;         // exact r4 ordering
    v[r] = RESL ? xr[r] + y : y;
  }
}

template<int L>
__device__ __forceinline__ void loadw_A(float (&w)[16], const float* lds_bw, int lane) {
  constexpr int n = VECLEN >> L;
  constexpr int off = 2048 - (2048 >> L);
  const int f0 = off + ((lane * 16) & (n - 1));
#pragma unroll
  for (int k = 0; k < 4; ++k) {
    const float4 f = *reinterpret_cast<const float4*>(lds_bw + swz(f0 + 4*k));
    w[4*k+0]=f.x; w[4*k+1]=f.y; w[4*k+2]=f.z; w[4*k+3]=f.w;
  }
}

// B-layout (e = r*64 + lane) twiddles: nr = n/64 distinct values per lane.
template<int L>
__device__ __forceinline__ void loadw_B(float* w, const float* lds_bw, int lane) {
  constexpr int off = 2048 - (2048 >> L);
  constexpr int nr = (VECLEN >> L) >> 6;   // 16, 8, 4, 2
#pragma unroll
  for (int j = 0; j < nr; ++j)
    w[j] = lds_bw[swz(off + j*64 + lane)];
}

// B-layout in-lane levels (3..0): partner flips r-bit hb = nr/2; twiddle w[r & (nr-1)].
template<int L, bool RESL>
__device__ __forceinline__ void level_B(float (&v)[16], const float (&xr)[16],
                                        const float* w, const float* __restrict__ lw) {
  constexpr int nr = (VECLEN >> L) >> 6;   // 16, 8, 4, 2
  constexpr int hb = nr >> 1;              // 8, 4, 2, 1
  const float l00 = lw[L*4+0], l01 = lw[L*4+1], l10 = lw[L*4+2], l11 = lw[L*4+3];
#pragma unroll
  for (int r = 0; r < 16; ++r) {
    if ((r & hb) == 0) {
      const int q = r ^ hb;
      const float t0 = w[r & (nr-1)] * v[r];
      const float t1 = w[q & (nr-1)] * v[q];
      const float y0 = l00*t0 + l10*t1;
      const float y1 = l01*t0 + l11*t1;
      v[r] = RESL ? xr[r] + y0 : y0;
      v[q] = RESL ? xr[q] + y1 : y1;
    }
  }
}

__global__ __launch_bounds__(256)
void rnnfft_kernel(const float* __restrict__ x,
                   const float* __restrict__ bw,
                   const float* __restrict__ lw,
                   float* __restrict__ out, int nvec) {
  __shared__ float lds_bw[2048];           // swizzled bw[0..2016)
  __shared__ float tbuf[4][1024];          // per-wave transpose buffer (16 KB)
  const int t = threadIdx.x;
  const int w4 = t >> 6;
  const int lane = t & 63;
  const int wid = blockIdx.x * 4 + w4;     // wave id = vector id (grid exact)
  const size_t base = (size_t)wid * VECLEN;

  // x in layout A (for levels 9..4 residuals) and layout B (for levels 3..0),
  // both issued up front - same cachelines, second read L1/L2-hits.
  float v[16], xrA[16], xrB[16];
#pragma unroll
  for (int k = 0; k < 4; ++k) {
    const float4 f = *reinterpret_cast<const float4*>(x + base + lane*16 + 4*k);
    xrA[4*k+0]=f.x; xrA[4*k+1]=f.y; xrA[4*k+2]=f.z; xrA[4*k+3]=f.w;
  }
#pragma unroll
  for (int r = 0; r < 16; ++r) xrB[r] = x[base + r*64 + lane];

  // Stage bw[0..2016) into LDS (swizzled), once per block.
  if (t < 252) {
    const float4 a = *reinterpret_cast<const float4*>(bw + 8*t);
    const float4 b = *reinterpret_cast<const float4*>(bw + 8*t + 4);
    *reinterpret_cast<float4*>(lds_bw + swz(8*t)) = a;
    *reinterpret_cast<float4*>(lds_bw + swz(8*t+4)) = b;
  }
  __syncthreads();

#pragma unroll
  for (int r = 0; r < 16; ++r) v[r] = xrA[r];

  // Prefetch A-level DPP twiddles from LDS (land during in-lane levels).
  float wA[16], wB[16];
  loadw_A<5>(wA, lds_bw, lane);
  loadw_A<4>(wB, lds_bw, lane);

  // Layout A: levels 9..6 in-lane, 5 and 4 via DPP.
  level_inlane<9, true>(v, xrA, bw, lw);
  level_inlane<8, true>(v, xrA, bw, lw);
  level_inlane<7, true>(v, xrA, bw, lw);
  level_inlane<6, true>(v, xrA, bw, lw);
  level_dpp<5, true>(v, xrA, wA, lw, lane);
  level_dpp<4, true>(v, xrA, wB, lw, lane);

  // Transpose v: A -> B through per-wave LDS buffer (swizzled, ~conflict-free).
  float* buf = tbuf[w4];
#pragma unroll
  for (int k = 0; k < 4; ++k) {
    float4 f;
    f.x = v[4*k+0]; f.y = v[4*k+1]; f.z = v[4*k+2]; f.w = v[4*k+3];
    *reinterpret_cast<float4*>(buf + swz(lane*16 + 4*k)) = f;
  }
  // B-twiddles for first two B-levels ride the same DS queue.
  float w3[2], w2[4], w1[8], w0[16];
  loadw_B<3>(w3, lds_bw, lane);
  loadw_B<2>(w2, lds_bw, lane);
#pragma unroll
  for (int r = 0; r < 16; ++r) v[r] = buf[swz(r*64 + lane)];

  // Layout B: levels 3..0 all in-lane (pure VALU).
  level_B<3, true >(v, xrB, w3, lw);
  loadw_B<1>(w1, lds_bw, lane);
  level_B<2, true >(v, xrB, w2, lw);
  loadw_B<0>(w0, lds_bw, lane);
  level_B<1, false>(v, xrB, w1, lw);   // RES[1] = False
  level_B<0, true >(v, xrB, w0, lw);

  // Store directly in B-layout: 16 coalesced 256B dword stores.
#pragma unroll
  for (int r = 0; r < 16; ++r) out[base + r*64 + lane] = v[r];
}

extern "C" void kernel_launch(void* const* d_in, const int* in_sizes, int n_in,
                              void* d_out, int out_size, void* d_ws, size_t ws_size,
                              hipStream_t stream) {
  const float* x  = (const float*)d_in[0];
  const float* bw = (const float*)d_in[1];
  const float* lw = (const float*)d_in[2];
  float* out = (float*)d_out;
  const int nvec = in_sizes[0] / VECLEN;        // 16384 vectors
  const int wpb = 4;                            // waves per block (256 threads)
  const int blocks = (nvec + wpb - 1) / wpb;    // 4096, exact
  rnnfft_kernel<<<blocks, 256, 0, stream>>>(x, bw, lw, out, nvec);
}